// Round 8
// baseline (1113.038 us; speedup 1.0000x reference)
//
#include <hip/hip_runtime.h>
#include <hip/hip_cooperative_groups.h>

namespace cg = cooperative_groups;

#define N_NODES 50000
#define N_EDGES 600000
#define IN_DIM  256
#define HID     128
#define BN_EPS  1e-5f

#define PRE_BLOCKS 1024
#define CHUNK 49                         // ceil(50000/1024)

typedef __attribute__((ext_vector_type(8))) short bf16x8;   // 8 bf16 = 4 VGPRs
typedef __attribute__((ext_vector_type(4))) float f32x4;

__device__ __forceinline__ ushort f2bf(float f) {           // RNE fp32->bf16
    union { float f; uint u; } v; v.f = f;
    return (ushort)((v.u + 0x7FFFu + ((v.u >> 16) & 1u)) >> 16);
}
__device__ __forceinline__ float bflo(uint u) {
    union { uint u; float f; } v; v.u = u << 16; return v.f;
}
__device__ __forceinline__ float bfhi(uint u) {
    union { uint u; float f; } v; v.u = u & 0xFFFF0000u; return v.f;
}

// ---------------------------------------------------------------------------
// Cooperative preprocessing: zero -> hist+prepW -> scan(3 phases) -> fill.
// Replaces 5 dispatches. 1024 blocks x 256 threads (4 blocks/CU co-resident).
// ---------------------------------------------------------------------------
__global__ __launch_bounds__(256) void pre_kernel(const int* __restrict__ row,
                                                  const int* __restrict__ col,
                                                  const float* __restrict__ W,
                                                  int* cnt, float* dis,
                                                  int* rowptr, int* cursor,
                                                  int* blocksums, int* srcs,
                                                  ushort* Wt, float* colstats) {
    cg::grid_group grid = cg::this_grid();
    const int t = threadIdx.x, b = blockIdx.x;
    const int gtid = b * 256 + t;
    const int gsz = PRE_BLOCKS * 256;

    // ---- A: zero counters + stats accumulators
    for (int i = gtid; i < N_NODES; i += gsz) cnt[i] = 0;
    if (gtid < 256) colstats[gtid] = 0.0f;
    __threadfence();
    grid.sync();

    // ---- B: in-degree histogram (targets) + W -> Wt bf16 transpose
    for (int i = gtid; i < N_EDGES; i += gsz) atomicAdd(&cnt[col[i]], 1);
    for (int i = gtid; i < IN_DIM * HID; i += gsz) {
        int n = i >> 8, k = i & 255;
        Wt[n * IN_DIM + k] = f2bf(W[(size_t)k * HID + n]);
    }
    __threadfence();
    grid.sync();

    // ---- C1: per-block chunk sums (49 elems/block)
    __shared__ int ls[64];
    {
        int i = b * CHUNK + t;
        int v = (t < CHUNK && i < N_NODES) ? cnt[i] : 0;
        if (t < 64) ls[t] = (t < CHUNK) ? v : 0;
        __syncthreads();
        if (t == 0) {
            int s = 0;
            for (int j = 0; j < CHUNK; j++) s += ls[j];
            blocksums[b] = s;
        }
    }
    __threadfence();
    grid.sync();

    // ---- C2: block 0 exclusive-scans blocksums[1024] in place
    if (b == 0) {
        __shared__ int ts[256];
        int base = t * 4;
        int v0 = blocksums[base], v1 = blocksums[base + 1];
        int v2 = blocksums[base + 2], v3 = blocksums[base + 3];
        int s = v0 + v1 + v2 + v3;
        ts[t] = s;
        __syncthreads();
        for (int off = 1; off < 256; off <<= 1) {
            int x = 0;
            if (t >= off) x = ts[t - off];
            __syncthreads();
            if (t >= off) ts[t] += x;
            __syncthreads();
        }
        int excl = ts[t] - s;
        blocksums[base]     = excl;
        blocksums[base + 1] = excl + v0;
        blocksums[base + 2] = excl + v0 + v1;
        blocksums[base + 3] = excl + v0 + v1 + v2;
    }
    __threadfence();
    grid.sync();

    // ---- C3: per-block exclusive scan of chunk -> rowptr/cursor/dis
    {
        __shared__ int off49[CHUNK + 1];
        int i = b * CHUNK + t;
        int v = (t < CHUNK && i < N_NODES) ? cnt[i] : 0;
        if (t < 64) ls[t] = (t < CHUNK) ? v : 0;
        __syncthreads();
        if (t == 0) {
            int s = blocksums[b];
            for (int j = 0; j < CHUNK; j++) { off49[j] = s; s += ls[j]; }
            off49[CHUNK] = s;
        }
        __syncthreads();
        if (t < CHUNK && i < N_NODES) {
            int excl = off49[t];
            rowptr[i] = excl;
            cursor[i] = excl;
            dis[i] = rsqrtf((float)v + 1.0f);   // +1 = self loop
        }
        if (gtid == 0) rowptr[N_NODES] = N_EDGES;
    }
    __threadfence();
    grid.sync();

    // ---- D: fill CSR: srcs[cursor[col]++] = row
    for (int i = gtid; i < N_EDGES; i += gsz) {
        int c = col[i];
        int pos = atomicAdd(&cursor[c], 1);
        srcs[pos] = row[i];
    }
}

// ---------------------------------------------------------------------------
// GEMM via MFMA: h2[M,128](bf16) = (x[M,256] @ W[256,128]) * dis[row]
// (pre-scaling by dis[src] removes the per-edge dis load in gather:
//  out[n] = dis[n] * (h2[n] + sum_{s in N(n)} h2[s]))
// ---------------------------------------------------------------------------
#define LDA 40

__global__ __launch_bounds__(256) void gemm_kernel(const float* __restrict__ x,
                                                   const ushort* __restrict__ Wt,
                                                   const float* __restrict__ dis,
                                                   ushort* __restrict__ h2, int M) {
    __shared__ ushort As[64][LDA];
    __shared__ ushort Bs[128][LDA];
    const int t = threadIdx.x;
    const int row0 = blockIdx.x * 64;
    const int wave = t >> 6, lane = t & 63;
    const int lrow = lane & 15, quad = lane >> 4;

    f32x4 acc[8];
    #pragma unroll
    for (int c = 0; c < 8; c++) acc[c] = (f32x4){0.f, 0.f, 0.f, 0.f};

    const int arow = t >> 2, aq = t & 3;
    const int bn = t >> 1, bh = t & 1;

    for (int k0 = 0; k0 < IN_DIM; k0 += 32) {
        {
            int gr = row0 + arow;
            uint4 pk = make_uint4(0, 0, 0, 0);
            if (gr < M) {
                const float* src = x + (size_t)gr * IN_DIM + k0 + aq * 8;
                float4 f0 = *(const float4*)src;
                float4 f1 = *(const float4*)(src + 4);
                pk.x = f2bf(f0.x) | ((uint)f2bf(f0.y) << 16);
                pk.y = f2bf(f0.z) | ((uint)f2bf(f0.w) << 16);
                pk.z = f2bf(f1.x) | ((uint)f2bf(f1.y) << 16);
                pk.w = f2bf(f1.z) | ((uint)f2bf(f1.w) << 16);
            }
            *(uint4*)&As[arow][aq * 8] = pk;
        }
        {
            const uint4* src = (const uint4*)(Wt + (size_t)bn * IN_DIM + k0 + bh * 16);
            *(uint4*)&Bs[bn][bh * 16]     = src[0];
            *(uint4*)&Bs[bn][bh * 16 + 8] = src[1];
        }
        __syncthreads();

        bf16x8 af = *(const bf16x8*)&As[wave * 16 + lrow][quad * 8];
        #pragma unroll
        for (int c = 0; c < 8; c++) {
            bf16x8 bfr = *(const bf16x8*)&Bs[c * 16 + lrow][quad * 8];
            acc[c] = __builtin_amdgcn_mfma_f32_16x16x32_bf16(af, bfr, acc[c], 0, 0, 0);
        }
        __syncthreads();
    }

    #pragma unroll
    for (int r = 0; r < 4; r++) {
        int gr = row0 + wave * 16 + quad * 4 + r;
        if (gr < M) {
            float dsc = dis[gr];
            #pragma unroll
            for (int c = 0; c < 8; c++)
                h2[(size_t)gr * HID + c * 16 + lrow] = f2bf(acc[c][r] * dsc);
        }
    }
}

// ---------------------------------------------------------------------------
// Gather + fused column stats (unchanged from R7).
// ---------------------------------------------------------------------------
#define GATHER_BLOCKS 2048
#define GW 4

__global__ __launch_bounds__(256) void gather_kernel(const int* __restrict__ rowptr,
                                                     const int* __restrict__ srcs,
                                                     const float* __restrict__ dis,
                                                     const uint* __restrict__ h2,   // 64 uints/row
                                                     float* __restrict__ out,
                                                     float* colsum, float* colsumsq) {
    const int wave = threadIdx.x >> 6, lane = threadIdx.x & 63;
    const int g = lane >> 4, l16 = lane & 15;
    float s[8], q[8];
    #pragma unroll
    for (int j = 0; j < 8; j++) { s[j] = 0.f; q[j] = 0.f; }

    for (int node = blockIdx.x * GW + wave; node < N_NODES; node += GATHER_BLOCKS * GW) {
        int beg = rowptr[node], end = rowptr[node + 1];
        float dn = dis[node];
        float acc[8];
        #pragma unroll
        for (int j = 0; j < 8; j++) acc[j] = 0.f;

        for (int base = beg; base < end; base += 16) {
            int idx[4];
            uint4 rw[4];
            #pragma unroll
            for (int u = 0; u < 4; u++) {
                int e = base + g + 4 * u;
                idx[u] = (e < end) ? srcs[e] : -1;   // 16 ints = 1 cache line
            }
            #pragma unroll
            for (int u = 0; u < 4; u++) {
                int si = (idx[u] >= 0) ? idx[u] : 0;
                rw[u] = *(const uint4*)(h2 + (size_t)si * 64 + l16 * 4);
            }
            #pragma unroll
            for (int u = 0; u < 4; u++) {
                if (idx[u] >= 0) {
                    acc[0] += bflo(rw[u].x); acc[1] += bfhi(rw[u].x);
                    acc[2] += bflo(rw[u].y); acc[3] += bfhi(rw[u].y);
                    acc[4] += bflo(rw[u].z); acc[5] += bfhi(rw[u].z);
                    acc[6] += bflo(rw[u].w); acc[7] += bfhi(rw[u].w);
                }
            }
        }

        #pragma unroll
        for (int j = 0; j < 8; j++) {
            acc[j] += __shfl_xor(acc[j], 16, 64);
            acc[j] += __shfl_xor(acc[j], 32, 64);
        }

        uint4 self = *(const uint4*)(h2 + (size_t)node * 64 + l16 * 4);
        acc[0] += bflo(self.x); acc[1] += bfhi(self.x);
        acc[2] += bflo(self.y); acc[3] += bfhi(self.y);
        acc[4] += bflo(self.z); acc[5] += bfhi(self.z);
        acc[6] += bflo(self.w); acc[7] += bfhi(self.w);
        #pragma unroll
        for (int j = 0; j < 8; j++) acc[j] *= dn;

        if (g == 0) {
            float* op = out + (size_t)node * HID + l16 * 8;
            *(float4*)op       = make_float4(acc[0], acc[1], acc[2], acc[3]);
            *(float4*)(op + 4) = make_float4(acc[4], acc[5], acc[6], acc[7]);
            #pragma unroll
            for (int j = 0; j < 8; j++) {
                s[j] += acc[j];
                q[j] = fmaf(acc[j], acc[j], q[j]);
            }
        }
    }

    __shared__ float rs[GW][HID];
    __shared__ float rq[GW][HID];
    if (g == 0) {
        #pragma unroll
        for (int j = 0; j < 8; j++) {
            rs[wave][l16 * 8 + j] = s[j];
            rq[wave][l16 * 8 + j] = q[j];
        }
    }
    __syncthreads();
    int t = threadIdx.x;
    if (t < HID) {
        float ss = rs[0][t] + rs[1][t] + rs[2][t] + rs[3][t];
        float qq = rq[0][t] + rq[1][t] + rq[2][t] + rq[3][t];
        atomicAdd(&colsum[t], ss);
        atomicAdd(&colsumsq[t], qq);
    }
}

// ---------------------------------------------------------------------------
// BN (training stats, biased var) + ReLU, in place. (bias b cancels in BN)
// ---------------------------------------------------------------------------
__global__ __launch_bounds__(256) void bn_relu_kernel(float* __restrict__ out,
                                                      const float* __restrict__ colsum,
                                                      const float* __restrict__ colsumsq,
                                                      const float* __restrict__ gamma,
                                                      const float* __restrict__ beta, int M) {
    size_t i = (size_t)blockIdx.x * 256 + threadIdx.x;
    size_t total = (size_t)M * (HID / 4);
    if (i >= total) return;
    int c4 = (int)((i & (HID / 4 - 1)) * 4);
    float4 v = ((const float4*)out)[i];
    float vv[4] = {v.x, v.y, v.z, v.w};
    float res[4];
    const float invN = 1.0f / (float)M;
    #pragma unroll
    for (int j = 0; j < 4; j++) {
        int c = c4 + j;
        float mean = colsum[c] * invN;
        float var  = colsumsq[c] * invN - mean * mean;
        var = fmaxf(var, 0.0f);
        float sc = gamma[c] * rsqrtf(var + BN_EPS);
        res[j] = fmaxf(0.0f, (vv[j] - mean) * sc + beta[c]);
    }
    ((float4*)out)[i] = make_float4(res[0], res[1], res[2], res[3]);
}

// ---------------------------------------------------------------------------
extern "C" void kernel_launch(void* const* d_in, const int* in_sizes, int n_in,
                              void* d_out, int out_size, void* d_ws, size_t ws_size,
                              hipStream_t stream) {
    const float* x     = (const float*)d_in[0];
    const int*   ei    = (const int*)  d_in[1];   // [2,E] flat: row(src) then col(dst)
    const float* W     = (const float*)d_in[2];
    // d_in[3] = b: cancels inside BatchNorm -> unused
    const float* gamma = (const float*)d_in[4];
    const float* beta  = (const float*)d_in[5];
    float* out = (float*)d_out;

    const int* row = ei;
    const int* col = ei + N_EDGES;

    // workspace layout (4-byte words)
    int*    cnt       = (int*)d_ws;                        // [50000]
    float*  dis       = (float*)d_ws + 50000;              // [50000]
    int*    rowptr    = (int*)d_ws + 100000;               // [50001]
    int*    cursor    = (int*)d_ws + 150016;               // [50000]
    int*    blocksums = (int*)d_ws + 200016;               // [1024]
    int*    srcs      = (int*)d_ws + 201040;               // [600000]
    ushort* Wt        = (ushort*)((int*)d_ws + 801040);    // [128*256] bf16 (16384 words)
    ushort* h2        = (ushort*)((int*)d_ws + 817424);    // [50000*128] bf16 (3.2M words)
    float*  colsum    = (float*)d_ws + 4017424;            // [128]
    float*  colsumsq  = (float*)d_ws + 4017552;            // [128]

    {
        void* args[] = {
            (void*)&row, (void*)&col, (void*)&W,
            (void*)&cnt, (void*)&dis, (void*)&rowptr, (void*)&cursor,
            (void*)&blocksums, (void*)&srcs, (void*)&Wt, (void*)&colsum
        };
        hipLaunchCooperativeKernel((const void*)pre_kernel,
                                   dim3(PRE_BLOCKS), dim3(256), args, 0, stream);
    }

    gemm_kernel<<<(N_NODES + 63) / 64, 256, 0, stream>>>(x, Wt, dis, h2, N_NODES);

    gather_kernel<<<GATHER_BLOCKS, 256, 0, stream>>>(rowptr, srcs, dis, (const uint*)h2, out,
                                                     colsum, colsumsq);

    {
        size_t total = (size_t)N_NODES * (HID / 4);
        bn_relu_kernel<<<(int)((total + 255) / 256), 256, 0, stream>>>(out, colsum, colsumsq, gamma, beta, N_NODES);
    }
}

// Round 9
// 344.028 us; speedup vs baseline: 3.2353x; 3.2353x over previous
//
#include <hip/hip_runtime.h>

#define N_NODES 50000
#define N_EDGES 600000
#define IN_DIM  256
#define HID     128
#define BN_EPS  1e-5f

#define HIST_BLOCKS ((N_EDGES + 255) / 256)     // 2344
#define PREPW_BLOCKS ((IN_DIM * HID) / 256)     // 128
#define CHUNK 49                                // 1024*49 = 50176 >= 50000

#define GEMM_BLOCKS ((N_NODES + 63) / 64)       // 782
#define FILL_BLOCKS 1172                        // 1172*256*2 >= 600000

typedef __attribute__((ext_vector_type(8))) short bf16x8;   // 8 bf16 = 4 VGPRs
typedef __attribute__((ext_vector_type(4))) float f32x4;

__device__ __forceinline__ ushort f2bf(float f) {           // RNE fp32->bf16
    union { float f; uint u; } v; v.f = f;
    return (ushort)((v.u + 0x7FFFu + ((v.u >> 16) & 1u)) >> 16);
}
__device__ __forceinline__ float bflo(uint u) {
    union { uint u; float f; } v; v.u = u << 16; return v.f;
}
__device__ __forceinline__ float bfhi(uint u) {
    union { uint u; float f; } v; v.u = u & 0xFFFF0000u; return v.f;
}

// ---------------------------------------------------------------------------
// K1: in-degree histogram on targets; trailing blocks convert W -> Wt
// (bf16, transposed). cnt zeroed by the preceding hipMemsetAsync.
// ---------------------------------------------------------------------------
__global__ __launch_bounds__(256) void hist_prepw_kernel(const int* __restrict__ col, int* cnt,
                                                         const float* __restrict__ W, ushort* Wt) {
    int b = blockIdx.x;
    if (b < HIST_BLOCKS) {
        int i = b * 256 + threadIdx.x;
        if (i < N_EDGES) atomicAdd(&cnt[col[i]], 1);
    } else {
        int i = (b - HIST_BLOCKS) * 256 + threadIdx.x;  // 0 .. 32767
        int n = i >> 8, k = i & 255;
        Wt[n * IN_DIM + k] = f2bf(W[(size_t)k * HID + n]);
    }
}

// ---------------------------------------------------------------------------
// K2: whole exclusive scan in ONE 1024-thread block (replaces 2 kernels).
// Each thread owns 49 consecutive cnt entries in registers; LDS Hillis-Steele
// over the 1024 partial sums; writes rowptr/cursor/dis.
// (Dispatch boundaries are the cheap grid barrier on MI355X -- R8 showed
//  cg::grid_sync costs ~190 us/barrier across XCDs.)
// ---------------------------------------------------------------------------
__global__ __launch_bounds__(1024) void scan_kernel(const int* __restrict__ cnt,
                                                    int* rowptr, int* cursor, float* dis) {
    __shared__ int ts[1024];
    const int t = threadIdx.x;
    const int base = t * CHUNK;

    int vals[CHUNK];
    int s = 0;
    #pragma unroll
    for (int j = 0; j < CHUNK; j++) {
        int i = base + j;
        vals[j] = (i < N_NODES) ? cnt[i] : 0;
        s += vals[j];
    }
    ts[t] = s;
    __syncthreads();
    for (int off = 1; off < 1024; off <<= 1) {
        int x = 0;
        if (t >= off) x = ts[t - off];
        __syncthreads();
        if (t >= off) ts[t] += x;
        __syncthreads();
    }
    int run = ts[t] - s;   // exclusive prefix of this thread's chunk
    #pragma unroll
    for (int j = 0; j < CHUNK; j++) {
        int i = base + j;
        if (i < N_NODES) {
            rowptr[i] = run;
            cursor[i] = run;
            dis[i] = rsqrtf((float)vals[j] + 1.0f);   // +1 = self loop
        }
        run += vals[j];
    }
    if (t == 0) rowptr[N_NODES] = N_EDGES;
}

// ---------------------------------------------------------------------------
// K3: block-specialized gemm + fill (both depend only on K2; independent).
// blocks [0, GEMM_BLOCKS): h2[M,128](bf16) = (x @ W) * dis[row]  via MFMA
// blocks [GEMM_BLOCKS, +FILL_BLOCKS): srcs[cursor[col]++] = row  (CSR fill)
// ---------------------------------------------------------------------------
#define LDA 40

__global__ __launch_bounds__(256) void gemmfill_kernel(const float* __restrict__ x,
                                                       const ushort* __restrict__ Wt,
                                                       const float* __restrict__ dis,
                                                       ushort* __restrict__ h2,
                                                       const int* __restrict__ row,
                                                       const int* __restrict__ col,
                                                       int* cursor, int* srcs) {
    if (blockIdx.x >= GEMM_BLOCKS) {
        // ---- fill part: 2 edges per thread
        int idx = (blockIdx.x - GEMM_BLOCKS) * 256 + threadIdx.x;
        for (int i = idx; i < N_EDGES; i += FILL_BLOCKS * 256) {
            int c = col[i];
            int pos = atomicAdd(&cursor[c], 1);
            srcs[pos] = row[i];
        }
        return;
    }

    // ---- gemm part (identical to R7 gemm_kernel)
    __shared__ ushort As[64][LDA];
    __shared__ ushort Bs[128][LDA];
    const int t = threadIdx.x;
    const int row0 = blockIdx.x * 64;
    const int wave = t >> 6, lane = t & 63;
    const int lrow = lane & 15, quad = lane >> 4;
    const int M = N_NODES;

    f32x4 acc[8];
    #pragma unroll
    for (int c = 0; c < 8; c++) acc[c] = (f32x4){0.f, 0.f, 0.f, 0.f};

    const int arow = t >> 2, aq = t & 3;
    const int bn = t >> 1, bh = t & 1;

    for (int k0 = 0; k0 < IN_DIM; k0 += 32) {
        {
            int gr = row0 + arow;
            uint4 pk = make_uint4(0, 0, 0, 0);
            if (gr < M) {
                const float* src = x + (size_t)gr * IN_DIM + k0 + aq * 8;
                float4 f0 = *(const float4*)src;
                float4 f1 = *(const float4*)(src + 4);
                pk.x = f2bf(f0.x) | ((uint)f2bf(f0.y) << 16);
                pk.y = f2bf(f0.z) | ((uint)f2bf(f0.w) << 16);
                pk.z = f2bf(f1.x) | ((uint)f2bf(f1.y) << 16);
                pk.w = f2bf(f1.z) | ((uint)f2bf(f1.w) << 16);
            }
            *(uint4*)&As[arow][aq * 8] = pk;
        }
        {
            const uint4* src = (const uint4*)(Wt + (size_t)bn * IN_DIM + k0 + bh * 16);
            *(uint4*)&Bs[bn][bh * 16]     = src[0];
            *(uint4*)&Bs[bn][bh * 16 + 8] = src[1];
        }
        __syncthreads();

        bf16x8 af = *(const bf16x8*)&As[wave * 16 + lrow][quad * 8];
        #pragma unroll
        for (int c = 0; c < 8; c++) {
            bf16x8 bfr = *(const bf16x8*)&Bs[c * 16 + lrow][quad * 8];
            acc[c] = __builtin_amdgcn_mfma_f32_16x16x32_bf16(af, bfr, acc[c], 0, 0, 0);
        }
        __syncthreads();
    }

    #pragma unroll
    for (int r = 0; r < 4; r++) {
        int gr = row0 + wave * 16 + quad * 4 + r;
        if (gr < M) {
            float dsc = dis[gr];
            #pragma unroll
            for (int c = 0; c < 8; c++)
                h2[(size_t)gr * HID + c * 16 + lrow] = f2bf(acc[c][r] * dsc);
        }
    }
}

// ---------------------------------------------------------------------------
// K4: Gather + fused column stats (unchanged from R7).
// ---------------------------------------------------------------------------
#define GATHER_BLOCKS 2048
#define GW 4

__global__ __launch_bounds__(256) void gather_kernel(const int* __restrict__ rowptr,
                                                     const int* __restrict__ srcs,
                                                     const float* __restrict__ dis,
                                                     const uint* __restrict__ h2,   // 64 uints/row
                                                     float* __restrict__ out,
                                                     float* colsum, float* colsumsq) {
    const int wave = threadIdx.x >> 6, lane = threadIdx.x & 63;
    const int g = lane >> 4, l16 = lane & 15;
    float s[8], q[8];
    #pragma unroll
    for (int j = 0; j < 8; j++) { s[j] = 0.f; q[j] = 0.f; }

    for (int node = blockIdx.x * GW + wave; node < N_NODES; node += GATHER_BLOCKS * GW) {
        int beg = rowptr[node], end = rowptr[node + 1];
        float dn = dis[node];
        float acc[8];
        #pragma unroll
        for (int j = 0; j < 8; j++) acc[j] = 0.f;

        for (int base = beg; base < end; base += 16) {
            int idx[4];
            uint4 rw[4];
            #pragma unroll
            for (int u = 0; u < 4; u++) {
                int e = base + g + 4 * u;
                idx[u] = (e < end) ? srcs[e] : -1;   // 16 ints = 1 cache line
            }
            #pragma unroll
            for (int u = 0; u < 4; u++) {
                int si = (idx[u] >= 0) ? idx[u] : 0;
                rw[u] = *(const uint4*)(h2 + (size_t)si * 64 + l16 * 4);
            }
            #pragma unroll
            for (int u = 0; u < 4; u++) {
                if (idx[u] >= 0) {
                    acc[0] += bflo(rw[u].x); acc[1] += bfhi(rw[u].x);
                    acc[2] += bflo(rw[u].y); acc[3] += bfhi(rw[u].y);
                    acc[4] += bflo(rw[u].z); acc[5] += bfhi(rw[u].z);
                    acc[6] += bflo(rw[u].w); acc[7] += bfhi(rw[u].w);
                }
            }
        }

        #pragma unroll
        for (int j = 0; j < 8; j++) {
            acc[j] += __shfl_xor(acc[j], 16, 64);
            acc[j] += __shfl_xor(acc[j], 32, 64);
        }

        uint4 self = *(const uint4*)(h2 + (size_t)node * 64 + l16 * 4);
        acc[0] += bflo(self.x); acc[1] += bfhi(self.x);
        acc[2] += bflo(self.y); acc[3] += bfhi(self.y);
        acc[4] += bflo(self.z); acc[5] += bfhi(self.z);
        acc[6] += bflo(self.w); acc[7] += bfhi(self.w);
        #pragma unroll
        for (int j = 0; j < 8; j++) acc[j] *= dn;

        if (g == 0) {
            float* op = out + (size_t)node * HID + l16 * 8;
            *(float4*)op       = make_float4(acc[0], acc[1], acc[2], acc[3]);
            *(float4*)(op + 4) = make_float4(acc[4], acc[5], acc[6], acc[7]);
            #pragma unroll
            for (int j = 0; j < 8; j++) {
                s[j] += acc[j];
                q[j] = fmaf(acc[j], acc[j], q[j]);
            }
        }
    }

    __shared__ float rs[GW][HID];
    __shared__ float rq[GW][HID];
    if (g == 0) {
        #pragma unroll
        for (int j = 0; j < 8; j++) {
            rs[wave][l16 * 8 + j] = s[j];
            rq[wave][l16 * 8 + j] = q[j];
        }
    }
    __syncthreads();
    int t = threadIdx.x;
    if (t < HID) {
        float ss = rs[0][t] + rs[1][t] + rs[2][t] + rs[3][t];
        float qq = rq[0][t] + rq[1][t] + rq[2][t] + rq[3][t];
        atomicAdd(&colsum[t], ss);
        atomicAdd(&colsumsq[t], qq);
    }
}

// ---------------------------------------------------------------------------
// K5: BN (training stats, biased var) + ReLU, in place. (bias b cancels in BN)
// ---------------------------------------------------------------------------
__global__ __launch_bounds__(256) void bn_relu_kernel(float* __restrict__ out,
                                                      const float* __restrict__ colsum,
                                                      const float* __restrict__ colsumsq,
                                                      const float* __restrict__ gamma,
                                                      const float* __restrict__ beta, int M) {
    size_t i = (size_t)blockIdx.x * 256 + threadIdx.x;
    size_t total = (size_t)M * (HID / 4);
    if (i >= total) return;
    int c4 = (int)((i & (HID / 4 - 1)) * 4);
    float4 v = ((const float4*)out)[i];
    float vv[4] = {v.x, v.y, v.z, v.w};
    float res[4];
    const float invN = 1.0f / (float)M;
    #pragma unroll
    for (int j = 0; j < 4; j++) {
        int c = c4 + j;
        float mean = colsum[c] * invN;
        float var  = colsumsq[c] * invN - mean * mean;
        var = fmaxf(var, 0.0f);
        float sc = gamma[c] * rsqrtf(var + BN_EPS);
        res[j] = fmaxf(0.0f, (vv[j] - mean) * sc + beta[c]);
    }
    ((float4*)out)[i] = make_float4(res[0], res[1], res[2], res[3]);
}

// ---------------------------------------------------------------------------
extern "C" void kernel_launch(void* const* d_in, const int* in_sizes, int n_in,
                              void* d_out, int out_size, void* d_ws, size_t ws_size,
                              hipStream_t stream) {
    const float* x     = (const float*)d_in[0];
    const int*   ei    = (const int*)  d_in[1];   // [2,E] flat: row(src) then col(dst)
    const float* W     = (const float*)d_in[2];
    // d_in[3] = b: cancels inside BatchNorm -> unused
    const float* gamma = (const float*)d_in[4];
    const float* beta  = (const float*)d_in[5];
    float* out = (float*)d_out;

    const int* row = ei;
    const int* col = ei + N_EDGES;

    // workspace layout (4-byte words). cnt|colsum|colsumsq contiguous so one
    // memset zeroes all three.
    int*    cnt       = (int*)d_ws;                        // [50000]
    float*  colsum    = (float*)d_ws + 50000;              // [128]
    float*  colsumsq  = (float*)d_ws + 50128;              // [128]
    float*  dis       = (float*)d_ws + 50256;              // [50000]
    int*    rowptr    = (int*)d_ws + 100256;               // [50001]
    int*    cursor    = (int*)d_ws + 150272;               // [50000]
    int*    srcs      = (int*)d_ws + 200272;               // [600000]
    ushort* Wt        = (ushort*)((int*)d_ws + 800272);    // [128*256] bf16 (16384 words)
    ushort* h2        = (ushort*)((int*)d_ws + 816656);    // [50000*128] bf16 (3.2M words)

    hipMemsetAsync(d_ws, 0, 50256 * sizeof(int), stream);  // cnt + colsum + colsumsq

    hist_prepw_kernel<<<HIST_BLOCKS + PREPW_BLOCKS, 256, 0, stream>>>(col, cnt, W, Wt);

    scan_kernel<<<1, 1024, 0, stream>>>(cnt, rowptr, cursor, dis);

    gemmfill_kernel<<<GEMM_BLOCKS + FILL_BLOCKS, 256, 0, stream>>>(x, Wt, dis, h2,
                                                                   row, col, cursor, srcs);

    gather_kernel<<<GATHER_BLOCKS, 256, 0, stream>>>(rowptr, srcs, dis, (const uint*)h2, out,
                                                     colsum, colsumsq);

    {
        size_t total = (size_t)N_NODES * (HID / 4);
        bn_relu_kernel<<<(int)((total + 255) / 256), 256, 0, stream>>>(out, colsum, colsumsq, gamma, beta, N_NODES);
    }
}